// Round 1
// baseline (211.344 us; speedup 1.0000x reference)
//
#include <hip/hip_runtime.h>

#define NUM_CATEGORIES 64
#define IN_DIM 1024
#define OUT_DIM 1024
#define BATCH 32
#define SEQ 512

#define BM 128
#define BN 128
#define BK 64
#define LDA 72   // elems (bf16), A row stride: 144 B, 16B-aligned, breaks pow2 conflicts
#define LDB 72   // elems (bf16), Bt row stride

typedef float f32x4 __attribute__((ext_vector_type(4)));
typedef unsigned int u32x2 __attribute__((ext_vector_type(2)));
typedef __bf16 bf16x8 __attribute__((ext_vector_type(8)));

__device__ inline unsigned int f2bf_rne(float f) {
    unsigned int u = __builtin_bit_cast(unsigned int, f);
    return (u + 0x7FFFu + ((u >> 16) & 1u)) >> 16;
}
__device__ inline unsigned int pack2(float lo, float hi) {
    return f2bf_rne(lo) | (f2bf_rne(hi) << 16);
}

__global__ __launch_bounds__(256, 2)
void cslinear_kernel(const float* __restrict__ x,
                     const int* __restrict__ cid,
                     const float* __restrict__ weight,
                     const float* __restrict__ bias,
                     float* __restrict__ out) {
    __shared__ unsigned short As[BM * LDA];   // As[m][k]  (bf16)
    __shared__ unsigned short Bs[BN * LDB];   // Bs[n][k]  (bf16, transposed W, k-swizzled)

    const int t    = threadIdx.x;
    const int lane = t & 63;
    const int w    = t >> 6;

    const int nt = blockIdx.x;   // 0..7   n-tile
    const int mt = blockIdx.y;   // 0..3   m-tile
    const int b  = blockIdx.z;   // 0..31  batch

    const int c = cid[b];
    const float* Wp = weight + (size_t)c * IN_DIM * OUT_DIM + (size_t)nt * BN;
    const float* Xp = x + ((size_t)b * SEQ + (size_t)mt * BM) * IN_DIM;
    float* Op = out + ((size_t)b * SEQ + (size_t)mt * BM) * OUT_DIM + (size_t)nt * BN;

    f32x4 acc[4][4] = {};

    const int mbase = (w >> 1) * 64;
    const int nbase = (w & 1) * 64;
    const int lrow  = lane & 15;
    const int lkoff = (lane >> 4) << 4;   // byte offset of this lane's 16B k-chunk

    char* AsB = reinterpret_cast<char*>(As);
    char* BsB = reinterpret_cast<char*>(Bs);

    for (int ks = 0; ks < IN_DIM / BK; ++ks) {
        const int k0g = ks * BK;

        // ---- stage A: 128x64 f32 -> bf16, row-major [m][k] ----
        #pragma unroll
        for (int i = 0; i < 8; ++i) {
            int f   = i * 256 + t;          // 0..2047 float4 units
            int row = f >> 4;               // 0..127
            int c4  = f & 15;               // 0..15 -> k float4 index
            f32x4 v = *reinterpret_cast<const f32x4*>(Xp + (size_t)row * IN_DIM + k0g + c4 * 4);
            u32x2 p;
            p.x = pack2(v.x, v.y);
            p.y = pack2(v.z, v.w);
            *reinterpret_cast<u32x2*>(AsB + row * (LDA * 2) + c4 * 8) = p;
        }

        // ---- stage B: 64x128 f32 rows -> transposed bf16 Bs[n][k], swizzled ----
        #pragma unroll
        for (int i = 0; i < 4; ++i) {
            int u   = i * 256 + t;          // 0..1023 units (row-pair x col4)
            int rp  = u >> 5;               // 0..31  -> k0 = 2*rp
            int c4b = u & 31;               // 0..31  -> n = c4b*4
            int k0  = rp * 2;
            const float* base = Wp + (size_t)(k0g + k0) * OUT_DIM + c4b * 4;
            f32x4 r0 = *reinterpret_cast<const f32x4*>(base);
            f32x4 r1 = *reinterpret_cast<const f32x4*>(base + OUT_DIM);
            #pragma unroll
            for (int j = 0; j < 4; ++j) {
                int n = c4b * 4 + j;
                float lo = (j == 0) ? r0.x : (j == 1) ? r0.y : (j == 2) ? r0.z : r0.w;
                float hi = (j == 0) ? r1.x : (j == 1) ? r1.y : (j == 2) ? r1.z : r1.w;
                int kb = (k0 * 2) ^ ((n & 0x38) << 1);   // swizzle k-byte by n bits 3..5
                *reinterpret_cast<unsigned int*>(BsB + n * (LDB * 2) + kb) = pack2(lo, hi);
            }
        }

        __syncthreads();

        // ---- compute: 2 k-chunks of 32 ----
        #pragma unroll
        for (int kk = 0; kk < 2; ++kk) {
            bf16x8 afr[4], bfr[4];
            #pragma unroll
            for (int mi = 0; mi < 4; ++mi) {
                int r = mbase + mi * 16 + lrow;
                afr[mi] = *reinterpret_cast<const bf16x8*>(AsB + r * (LDA * 2) + kk * 64 + lkoff);
            }
            #pragma unroll
            for (int ni = 0; ni < 4; ++ni) {
                int n  = nbase + ni * 16 + lrow;
                int kb = (kk * 64 + lkoff) ^ ((n & 0x38) << 1);
                bfr[ni] = *reinterpret_cast<const bf16x8*>(BsB + n * (LDB * 2) + kb);
            }
            #pragma unroll
            for (int mi = 0; mi < 4; ++mi)
                #pragma unroll
                for (int ni = 0; ni < 4; ++ni)
                    acc[mi][ni] = __builtin_amdgcn_mfma_f32_16x16x32_bf16(
                        afr[mi], bfr[ni], acc[mi][ni], 0, 0, 0);
        }

        __syncthreads();
    }

    // ---- epilogue: C/D layout col=lane&15, row=(lane>>4)*4+reg ----
    const int lcol  = lane & 15;
    const int lrow4 = (lane >> 4) * 4;
    float bv[4];
    #pragma unroll
    for (int ni = 0; ni < 4; ++ni)
        bv[ni] = bias[(size_t)c * OUT_DIM + nt * BN + nbase + ni * 16 + lcol];

    #pragma unroll
    for (int mi = 0; mi < 4; ++mi) {
        int rbase = mbase + mi * 16 + lrow4;
        #pragma unroll
        for (int ni = 0; ni < 4; ++ni) {
            int ncol = nbase + ni * 16 + lcol;
            #pragma unroll
            for (int r = 0; r < 4; ++r) {
                Op[(size_t)(rbase + r) * OUT_DIM + ncol] = acc[mi][ni][r] + bv[ni];
            }
        }
    }
}

extern "C" void kernel_launch(void* const* d_in, const int* in_sizes, int n_in,
                              void* d_out, int out_size, void* d_ws, size_t ws_size,
                              hipStream_t stream) {
    const float* x      = (const float*)d_in[0];
    const int*   cid    = (const int*)d_in[1];
    const float* weight = (const float*)d_in[2];
    const float* bias   = (const float*)d_in[3];
    float* out = (float*)d_out;

    dim3 grid(OUT_DIM / BN, SEQ / BM, BATCH);
    dim3 block(256);
    hipLaunchKernelGGL(cslinear_kernel, grid, block, 0, stream,
                       x, cid, weight, bias, out);
}

// Round 2
// 109.746 us; speedup vs baseline: 1.9258x; 1.9258x over previous
//
#include <hip/hip_runtime.h>

#define NUM_CATEGORIES 64
#define IN_DIM 1024
#define OUT_DIM 1024
#define BATCH 32
#define SEQ 512

#define BM 128
#define BN 128
#define BK 64
#define LDA 72   // elems (bf16), A row stride: 144 B
#define LDB 72   // elems (bf16), Bt row stride
#define NSTEP (IN_DIM / BK)   // 16

typedef float f32x4 __attribute__((ext_vector_type(4)));
typedef unsigned int u32x2 __attribute__((ext_vector_type(2)));
typedef __bf16 bf16x8 __attribute__((ext_vector_type(8)));

__device__ inline unsigned int f2bf_rne(float f) {
    unsigned int u = __builtin_bit_cast(unsigned int, f);
    return (u + 0x7FFFu + ((u >> 16) & 1u)) >> 16;
}
__device__ inline unsigned int pack2(float lo, float hi) {
    return f2bf_rne(lo) | (f2bf_rne(hi) << 16);
}

__global__ __launch_bounds__(256, 2)
void cslinear_kernel(const float* __restrict__ x,
                     const int* __restrict__ cid,
                     const float* __restrict__ weight,
                     const float* __restrict__ bias,
                     float* __restrict__ out) {
    // double-buffered LDS (72 KB total -> 2 blocks/CU)
    __shared__ unsigned short As[2][BM * LDA];   // As[m][k]  (bf16)
    __shared__ unsigned short Bs[2][BN * LDB];   // Bs[n][k]  (bf16, k-swizzled)

    const int t    = threadIdx.x;
    const int lane = t & 63;
    const int w    = t >> 6;

    const int nt = blockIdx.x;   // 0..7   n-tile
    const int mt = blockIdx.y;   // 0..3   m-tile
    const int b  = blockIdx.z;   // 0..31  batch

    const int c = cid[b];
    const float* Wp = weight + (size_t)c * IN_DIM * OUT_DIM + (size_t)nt * BN;
    const float* Xp = x + ((size_t)b * SEQ + (size_t)mt * BM) * IN_DIM;
    float* Op = out + ((size_t)b * SEQ + (size_t)mt * BM) * OUT_DIM + (size_t)nt * BN;

    f32x4 acc[4][4] = {};

    const int mbase = (w >> 1) * 64;
    const int nbase = (w & 1) * 64;
    const int lrow  = lane & 15;
    const int lkoff = (lane >> 4) << 4;   // byte offset of this lane's 16B k-chunk

    // explicit staging registers: forces ALL tile loads in flight at once
    f32x4 ra[8];
    f32x4 rb0[4], rb1[4];

    // ---- issue all global loads for K-step ks into ra/rb (no waits here) ----
    auto LOADT = [&](int ks) {
        const float* Xk = Xp + ks * BK;
        #pragma unroll
        for (int i = 0; i < 8; ++i) {
            int f   = i * 256 + t;
            int row = f >> 4;
            int c4  = f & 15;
            ra[i] = *reinterpret_cast<const f32x4*>(Xk + (size_t)row * IN_DIM + c4 * 4);
        }
        const float* Wk = Wp + (size_t)(ks * BK) * OUT_DIM;
        #pragma unroll
        for (int i = 0; i < 4; ++i) {
            int u   = i * 256 + t;
            int rp  = u >> 5;
            int c4b = u & 31;
            const float* bse = Wk + (size_t)(rp * 2) * OUT_DIM + c4b * 4;
            rb0[i] = *reinterpret_cast<const f32x4*>(bse);
            rb1[i] = *reinterpret_cast<const f32x4*>(bse + OUT_DIM);
        }
    };

    // ---- pack staged regs to bf16 and write LDS buffer p ----
    auto STORET = [&](int p) {
        char* AsB = reinterpret_cast<char*>(&As[p][0]);
        char* BsB = reinterpret_cast<char*>(&Bs[p][0]);
        #pragma unroll
        for (int i = 0; i < 8; ++i) {
            int f   = i * 256 + t;
            int row = f >> 4;
            int c4  = f & 15;
            u32x2 q;
            q.x = pack2(ra[i].x, ra[i].y);
            q.y = pack2(ra[i].z, ra[i].w);
            *reinterpret_cast<u32x2*>(AsB + row * (LDA * 2) + c4 * 8) = q;
        }
        #pragma unroll
        for (int i = 0; i < 4; ++i) {
            int u   = i * 256 + t;
            int rp  = u >> 5;
            int c4b = u & 31;
            int k0  = rp * 2;
            #pragma unroll
            for (int j = 0; j < 4; ++j) {
                int n  = c4b * 4 + j;
                int kb = (k0 * 2) ^ ((n & 0x38) << 1);   // swizzle k-byte by n bits 3..5
                *reinterpret_cast<unsigned int*>(BsB + n * (LDB * 2) + kb) =
                    pack2(rb0[i][j], rb1[i][j]);
            }
        }
    };

    LOADT(0);

    for (int ks = 0; ks < NSTEP; ++ks) {
        const int p = ks & 1;

        // consume staged regs (compiler inserts counted vmcnt waits), write LDS[p]
        STORET(p);

        // issue next tile's global loads NOW -> in flight across barrier + MFMA
        if (ks + 1 < NSTEP) LOADT(ks + 1);

        // LDS writes must be visible; raw barrier does NOT drain vmcnt
        asm volatile("s_waitcnt lgkmcnt(0)" ::: "memory");
        __builtin_amdgcn_s_barrier();
        __builtin_amdgcn_sched_barrier(0);

        // ---- compute from buffer p: 2 k-chunks of 32 ----
        const char* AsB = reinterpret_cast<const char*>(&As[p][0]);
        const char* BsB = reinterpret_cast<const char*>(&Bs[p][0]);
        #pragma unroll
        for (int kk = 0; kk < 2; ++kk) {
            bf16x8 afr[4], bfr[4];
            #pragma unroll
            for (int mi = 0; mi < 4; ++mi) {
                int r = mbase + mi * 16 + lrow;
                afr[mi] = *reinterpret_cast<const bf16x8*>(AsB + r * (LDA * 2) + kk * 64 + lkoff);
            }
            #pragma unroll
            for (int ni = 0; ni < 4; ++ni) {
                int n  = nbase + ni * 16 + lrow;
                int kb = (kk * 64 + lkoff) ^ ((n & 0x38) << 1);
                bfr[ni] = *reinterpret_cast<const bf16x8*>(BsB + n * (LDB * 2) + kb);
            }
            #pragma unroll
            for (int mi = 0; mi < 4; ++mi)
                #pragma unroll
                for (int ni = 0; ni < 4; ++ni)
                    acc[mi][ni] = __builtin_amdgcn_mfma_f32_16x16x32_bf16(
                        afr[mi], bfr[ni], acc[mi][ni], 0, 0, 0);
        }
        // no second barrier: double buffer + single barrier is sufficient
        // (writes to buffer p^1 next iter are separated from this iter's reads
        //  of p^1... by the barrier of the next iteration)
    }

    // ---- epilogue: C/D layout col=lane&15, row=(lane>>4)*4+reg ----
    const int lcol  = lane & 15;
    const int lrow4 = (lane >> 4) * 4;
    float bv[4];
    #pragma unroll
    for (int ni = 0; ni < 4; ++ni)
        bv[ni] = bias[(size_t)c * OUT_DIM + nt * BN + nbase + ni * 16 + lcol];

    #pragma unroll
    for (int mi = 0; mi < 4; ++mi) {
        int rbase = mbase + mi * 16 + lrow4;
        #pragma unroll
        for (int ni = 0; ni < 4; ++ni) {
            int ncol = nbase + ni * 16 + lcol;
            #pragma unroll
            for (int r = 0; r < 4; ++r) {
                Op[(size_t)(rbase + r) * OUT_DIM + ncol] = acc[mi][ni][r] + bv[ni];
            }
        }
    }
}

extern "C" void kernel_launch(void* const* d_in, const int* in_sizes, int n_in,
                              void* d_out, int out_size, void* d_ws, size_t ws_size,
                              hipStream_t stream) {
    const float* x      = (const float*)d_in[0];
    const int*   cid    = (const int*)d_in[1];
    const float* weight = (const float*)d_in[2];
    const float* bias   = (const float*)d_in[3];
    float* out = (float*)d_out;

    dim3 grid(OUT_DIM / BN, SEQ / BM, BATCH);
    dim3 block(256);
    hipLaunchKernelGGL(cslinear_kernel, grid, block, 0, stream,
                       x, cid, weight, bias, out);
}

// Round 3
// 79.284 us; speedup vs baseline: 2.6656x; 1.3842x over previous
//
#include <hip/hip_runtime.h>

#define NUM_CATEGORIES 64
#define IN_DIM 1024
#define OUT_DIM 1024
#define BATCH 32
#define SEQ 512

#define BM 256
#define BN 256
#define BK 32
#define NSTEP (IN_DIM / BK)   // 32

#define LDA 40     // bf16 elems per A row (64B data + 16B pad), 16B-aligned
#define LDBW 260   // u32 words per B k-pair row (256 data + 4 pad), 16B-aligned

typedef float f32x4 __attribute__((ext_vector_type(4)));
typedef unsigned int u32x2 __attribute__((ext_vector_type(2)));
typedef unsigned int u32x4 __attribute__((ext_vector_type(4)));
typedef __bf16 bf16x8 __attribute__((ext_vector_type(8)));

__device__ inline unsigned int f2bf_rne(float f) {
    unsigned int u = __builtin_bit_cast(unsigned int, f);
    return (u + 0x7FFFu + ((u >> 16) & 1u)) >> 16;
}
__device__ inline unsigned int pack2(float lo, float hi) {
    return f2bf_rne(lo) | (f2bf_rne(hi) << 16);
}

__global__ __launch_bounds__(512, 2)
void cslinear_kernel(const float* __restrict__ x,
                     const int* __restrict__ cid,
                     const float* __restrict__ weight,
                     const float* __restrict__ bias,
                     float* __restrict__ out) {
    // A: [m][k] bf16 rows (padded). B: u32 k-pair words, [kp][n] (padded).
    __shared__ unsigned short As[2][BM * LDA];          // 2 x 20 KB
    __shared__ unsigned int   Bs[2][(BK / 2) * LDBW];   // 2 x 16.25 KB

    const int t    = threadIdx.x;
    const int lane = t & 63;
    const int w    = t >> 6;      // 0..7

    const int nt = blockIdx.x;    // 0..3
    const int mt = blockIdx.y;    // 0..1
    const int b  = blockIdx.z;    // 0..31

    const int c = cid[b];
    const float* Wp = weight + (size_t)c * IN_DIM * OUT_DIM + (size_t)nt * BN;
    const float* Xp = x + ((size_t)b * SEQ + (size_t)mt * BM) * IN_DIM;
    float* Op = out + ((size_t)b * SEQ + (size_t)mt * BM) * OUT_DIM + (size_t)nt * BN;

    f32x4 acc[8][4] = {};         // wave tile 128(m) x 64(n)

    const int mbase = (w >> 2) * 128;   // 0 or 128
    const int nbase = (w & 3) * 64;     // 0,64,128,192
    const int lrow  = lane & 15;
    const int lhi   = lane >> 4;        // 0..3 -> k-chunk

    // staging registers (all of a tile's loads in flight at once)
    f32x4 ra[4];          // A: 4 x f32x4
    f32x4 rb0[2], rb1[2]; // B: 2 units x (row k, row k+1)

    auto LOADT = [&](int ks) {
        const float* Xk = Xp + ks * BK;
        #pragma unroll
        for (int i = 0; i < 4; ++i) {
            int f   = i * 512 + t;        // 0..2047
            int row = f >> 3;             // 0..255
            int c4  = f & 7;              // 0..7
            ra[i] = *reinterpret_cast<const f32x4*>(Xk + (size_t)row * IN_DIM + c4 * 4);
        }
        const float* Wk = Wp + (size_t)(ks * BK) * OUT_DIM;
        #pragma unroll
        for (int i = 0; i < 2; ++i) {
            int u  = i * 512 + t;         // 0..1023
            int kp = u >> 6;              // 0..15
            int n4 = u & 63;              // 0..63
            const float* bse = Wk + (size_t)(2 * kp) * OUT_DIM + n4 * 4;
            rb0[i] = *reinterpret_cast<const f32x4*>(bse);
            rb1[i] = *reinterpret_cast<const f32x4*>(bse + OUT_DIM);
        }
    };

    auto STORET = [&](int p) {
        char* AsB = reinterpret_cast<char*>(&As[p][0]);
        #pragma unroll
        for (int i = 0; i < 4; ++i) {
            int f   = i * 512 + t;
            int row = f >> 3;
            int c4  = f & 7;
            u32x2 q;
            q.x = pack2(ra[i].x, ra[i].y);
            q.y = pack2(ra[i].z, ra[i].w);
            *reinterpret_cast<u32x2*>(AsB + row * (LDA * 2) + c4 * 8) = q;
        }
        unsigned int* BsW = &Bs[p][0];
        #pragma unroll
        for (int i = 0; i < 2; ++i) {
            int u  = i * 512 + t;
            int kp = u >> 6;
            int n4 = u & 63;
            u32x4 q;
            #pragma unroll
            for (int j = 0; j < 4; ++j)
                q[j] = pack2(rb0[i][j], rb1[i][j]);
            *reinterpret_cast<u32x4*>(BsW + kp * LDBW + n4 * 4) = q;  // contiguous b128
        }
    };

    LOADT(0);

    for (int ks = 0; ks < NSTEP; ++ks) {
        const int p = ks & 1;

        STORET(p);                         // waits staged regs (counted vmcnt)
        if (ks + 1 < NSTEP) LOADT(ks + 1); // next tile in flight across barrier

        asm volatile("s_waitcnt lgkmcnt(0)" ::: "memory");
        __builtin_amdgcn_s_barrier();
        __builtin_amdgcn_sched_barrier(0);

        const char* AsB = reinterpret_cast<const char*>(&As[p][0]);
        const unsigned int* BsW = &Bs[p][0];

        // B frags: 4 words each are exactly the bf16x8 (k-pairs in order)
        bf16x8 bfr[4];
        #pragma unroll
        for (int ni = 0; ni < 4; ++ni) {
            int n   = nbase + ni * 16 + lrow;
            int kp0 = lhi * 4;
            u32x4 wds;
            #pragma unroll
            for (int j = 0; j < 4; ++j)
                wds[j] = BsW[(kp0 + j) * LDBW + n];
            bfr[ni] = __builtin_bit_cast(bf16x8, wds);
        }

        #pragma unroll
        for (int mi = 0; mi < 8; ++mi) {
            int r = mbase + mi * 16 + lrow;
            bf16x8 afr = *reinterpret_cast<const bf16x8*>(AsB + r * (LDA * 2) + lhi * 16);
            #pragma unroll
            for (int ni = 0; ni < 4; ++ni)
                acc[mi][ni] = __builtin_amdgcn_mfma_f32_16x16x32_bf16(
                    afr, bfr[ni], acc[mi][ni], 0, 0, 0);
        }
        // single barrier per step is sufficient with double buffering
        // (prev compute of buffer p^1 is separated from next write by this barrier)
    }

    // epilogue: C/D layout col=lane&15, row=(lane>>4)*4+reg
    const int lcol  = lane & 15;
    const int lrow4 = (lane >> 4) * 4;
    float bv[4];
    #pragma unroll
    for (int ni = 0; ni < 4; ++ni)
        bv[ni] = bias[(size_t)c * OUT_DIM + nt * BN + nbase + ni * 16 + lcol];

    #pragma unroll
    for (int mi = 0; mi < 8; ++mi) {
        int rbase = mbase + mi * 16 + lrow4;
        #pragma unroll
        for (int ni = 0; ni < 4; ++ni) {
            int ncol = nbase + ni * 16 + lcol;
            #pragma unroll
            for (int r = 0; r < 4; ++r) {
                Op[(size_t)(rbase + r) * OUT_DIM + ncol] = acc[mi][ni][r] + bv[ni];
            }
        }
    }
}

extern "C" void kernel_launch(void* const* d_in, const int* in_sizes, int n_in,
                              void* d_out, int out_size, void* d_ws, size_t ws_size,
                              hipStream_t stream) {
    const float* x      = (const float*)d_in[0];
    const int*   cid    = (const int*)d_in[1];
    const float* weight = (const float*)d_in[2];
    const float* bias   = (const float*)d_in[3];
    float* out = (float*)d_out;

    dim3 grid(OUT_DIM / BN, SEQ / BM, BATCH);   // (4, 2, 32)
    dim3 block(512);
    hipLaunchKernelGGL(cslinear_kernel, grid, block, 0, stream,
                       x, cid, weight, bias, out);
}